// Round 17
// baseline (447.603 us; speedup 1.0000x reference)
//
#include <hip/hip_runtime.h>

#define N_NODES 100000
#define D_IN 64
#define HID 128
#define N_EDGES 1600000
#define N_LBL 500000
#define NBUCK 196   // ceil(100000/512) buckets of 512 dst nodes
#define NSCANB 98   // ceil(100000/1024) scan blocks
#define LCAP 3072   // label-edge bucket capacity (lambda=2560, sigma~51)

typedef __attribute__((ext_vector_type(8))) short bf16x8;
typedef __attribute__((ext_vector_type(4))) float f32x4;

// ---- bf16 helpers (RNE) ----
__device__ inline unsigned short f2bf(float f) {
  unsigned int u = __float_as_uint(f);
  return (unsigned short)((u + 0x7FFFu + ((u >> 16) & 1u)) >> 16);
}
__device__ inline float bf_lo(unsigned int w) { return __uint_as_float(w << 16); }
__device__ inline float bf_hi(unsigned int w) { return __uint_as_float(w & 0xFFFF0000u); }
__device__ inline float bfs(short s) {
  return __uint_as_float(((unsigned int)(unsigned short)s) << 16);
}

// ---------------- degree histogram (int) ----------------
__global__ __launch_bounds__(256) void k_deg(const int* __restrict__ dst,
                                             int* __restrict__ deg) {
  int e = blockIdx.x * 256 + threadIdx.x;
  if (e < N_EDGES) atomicAdd(&deg[dst[e]], 1);
}

// ---------------- scan phase A ----------------
__global__ __launch_bounds__(1024) void k_scan_a(const int* __restrict__ deg,
                                                 int* __restrict__ rowptr,
                                                 float* __restrict__ inv,
                                                 int* __restrict__ bsum) {
  __shared__ int s_wsum[16];
  const int lane = threadIdx.x & 63;
  const int wid = threadIdx.x >> 6;
  const int i = blockIdx.x * 1024 + threadIdx.x;
  int v = (i < N_NODES) ? deg[i] : 0;
  int x = v;
#pragma unroll
  for (int off = 1; off < 64; off <<= 1) {
    int t = __shfl_up(x, off);
    if (lane >= off) x += t;
  }
  if (lane == 63) s_wsum[wid] = x;
  __syncthreads();
  if (wid == 0 && lane < 16) {
    int ws = s_wsum[lane];
    int y = ws;
#pragma unroll
    for (int off = 1; off < 16; off <<= 1) {
      int t = __shfl_up(y, off);
      if (lane >= off) y += t;
    }
    s_wsum[lane] = y - ws;
    if (lane == 15) bsum[blockIdx.x] = y;
  }
  __syncthreads();
  if (i < N_NODES) {
    rowptr[i] = s_wsum[wid] + x - v;
    inv[i] = v > 0 ? 1.0f / (float)v : 0.0f;
  }
}

// ---------------- scan phase B ----------------
__global__ __launch_bounds__(128) void k_scan_b(int* __restrict__ bsum,
                                                int* __restrict__ rowptr) {
  __shared__ int s_w;
  const int tid = threadIdx.x;
  const int lane = tid & 63, wid = tid >> 6;
  int v = (tid < NSCANB) ? bsum[tid] : 0;
  int x = v;
#pragma unroll
  for (int off = 1; off < 64; off <<= 1) {
    int t = __shfl_up(x, off);
    if (lane >= off) x += t;
  }
  if (wid == 0 && lane == 63) s_w = x;
  __syncthreads();
  int incl = x + (wid == 1 ? s_w : 0);
  if (tid < NSCANB) bsum[tid] = incl - v;
  if (tid == NSCANB - 1) rowptr[N_NODES] = incl;
}

// ---------------- scan phase C ----------------
__global__ __launch_bounds__(1024) void k_scan_c(int* __restrict__ rowptr,
                                                 const int* __restrict__ bsum,
                                                 int* __restrict__ gcursor) {
  const int i = blockIdx.x * 1024 + threadIdx.x;
  if (i < N_NODES) {
    int r = rowptr[i] + bsum[blockIdx.x];
    rowptr[i] = r;
    if ((i & 511) == 0) gcursor[i >> 9] = r;
  }
}

// ---------------- bin graph edges by dst bucket ----------------
__global__ __launch_bounds__(256) void k_bin(const int* __restrict__ src,
                                             const int* __restrict__ dst,
                                             int* __restrict__ gcursor,
                                             int* __restrict__ binned) {
  __shared__ int hist[NBUCK];
  __shared__ int base[NBUCK];
  const int tid = threadIdx.x;
  const int e0 = blockIdx.x * 4096 + tid;
  for (int t = tid; t < NBUCK; t += 256) hist[t] = 0;
  __syncthreads();

  int w[16], bk[16], rk[16];
#pragma unroll
  for (int i = 0; i < 16; ++i) {
    int e = e0 + i * 256;
    if (e < N_EDGES) {
      int s = src[e], d = dst[e];
      bk[i] = d >> 9;
      w[i] = (s << 9) | (d & 511);
      rk[i] = atomicAdd(&hist[bk[i]], 1);
    } else {
      bk[i] = -1;
    }
  }
  __syncthreads();
  for (int t = tid; t < NBUCK; t += 256)
    base[t] = hist[t] > 0 ? atomicAdd(&gcursor[t], hist[t]) : 0;
  __syncthreads();
#pragma unroll
  for (int i = 0; i < 16; ++i)
    if (bk[i] >= 0) binned[base[bk[i]] + rk[i]] = w[i];
}

// ---------------- CSR fill from binned edges ----------------
__global__ __launch_bounds__(256) void k_fill2(const int* __restrict__ rowptr,
                                               const int* __restrict__ binned,
                                               int* __restrict__ csr) {
  __shared__ int lcur[512];
  const int b = blockIdx.x;
  const int nb = b << 9;
  const int nn = min(512, N_NODES - nb);
  for (int i = threadIdx.x; i < nn; i += 256) lcur[i] = rowptr[nb + i];
  __syncthreads();
  const int beg = rowptr[nb], end = rowptr[nb + nn];
  for (int e = beg + threadIdx.x; e < end; e += 256) {
    int w = binned[e];
    int pos = atomicAdd(&lcur[w & 511], 1);
    csr[pos] = w >> 9;
  }
}

// ---------------- bin label edges by src bucket (fixed-capacity regions) ----------------
__global__ __launch_bounds__(256) void k_lbl_bin(const int* __restrict__ ls,
                                                 const int* __restrict__ ld,
                                                 int* __restrict__ lblcnt,
                                                 int2* __restrict__ lbin) {
  __shared__ int hist[NBUCK];
  __shared__ int base[NBUCK];
  const int tid = threadIdx.x;
  const int e0 = blockIdx.x * 4096 + tid;
  for (int t = tid; t < NBUCK; t += 256) hist[t] = 0;
  __syncthreads();

  int dd[16], pk[16], bk[16], rk[16];
#pragma unroll
  for (int i = 0; i < 16; ++i) {
    int e = e0 + i * 256;
    if (e < N_LBL) {
      int s = ls[e];
      dd[i] = ld[e];
      bk[i] = s >> 9;
      pk[i] = (e << 9) | (s & 511);
      rk[i] = atomicAdd(&hist[bk[i]], 1);
    } else {
      bk[i] = -1;
    }
  }
  __syncthreads();
  for (int t = tid; t < NBUCK; t += 256)
    base[t] = hist[t] > 0 ? atomicAdd(&lblcnt[t], hist[t]) : 0;
  __syncthreads();
#pragma unroll
  for (int i = 0; i < 16; ++i)
    if (bk[i] >= 0) {
      int2 rec = {dd[i], pk[i]};
      lbin[(long)bk[i] * LCAP + base[bk[i]] + rk[i]] = rec;
    }
}

// ---------------- prep: x -> bf16; all weights -> bf16 transposed [n][k] ----------------
__global__ __launch_bounds__(256) void k_prep(
    const float* __restrict__ x, const float* __restrict__ w1l,
    const float* __restrict__ w1r, const float* __restrict__ w2l,
    const float* __restrict__ w2r, const float* __restrict__ dw1,
    unsigned short* __restrict__ x16, unsigned short* __restrict__ w1lt,
    unsigned short* __restrict__ w1rt, unsigned short* __restrict__ w2lt,
    unsigned short* __restrict__ w2rt, unsigned short* __restrict__ dw1t) {
  long gid = (long)blockIdx.x * 256 + threadIdx.x;
  if (gid < 1600000) {
    long i = gid * 4;
    float4 v = *(const float4*)&x[i];
    ushort4 q = {f2bf(v.x), f2bf(v.y), f2bf(v.z), f2bf(v.w)};
    *(ushort4*)&x16[i] = q;
    return;
  }
  long idx = gid - 1600000;
  if (idx < 8192) { int n = idx >> 6, k = idx & 63; w1lt[idx] = f2bf(w1l[k * 128 + n]); return; }
  idx -= 8192;
  if (idx < 8192) { int n = idx >> 6, k = idx & 63; w1rt[idx] = f2bf(w1r[k * 128 + n]); return; }
  idx -= 8192;
  if (idx < 16384) { int n = idx >> 7, k = idx & 127; w2lt[idx] = f2bf(w2l[k * 128 + n]); return; }
  idx -= 16384;
  if (idx < 16384) { int n = idx >> 7, k = idx & 127; w2rt[idx] = f2bf(w2r[k * 128 + n]); return; }
  idx -= 16384;
  if (idx < 32768) {
    int n = idx >> 7, k = idx & 127;
    dw1t[idx] = f2bf(n < 128 ? dw1[k * 128 + n] : dw1[(k + 128) * 128 + (n - 128)]);
  }
}

// ---------------- gather aggregation D=64 (bf16 in/out) ----------------
__global__ __launch_bounds__(256) void k_agg64(const int* __restrict__ rowptr,
                                               const int* __restrict__ csr,
                                               const unsigned short* __restrict__ f16,
                                               const float* __restrict__ inv,
                                               unsigned short* __restrict__ out16) {
  const int lane = threadIdx.x & 63;
  const int n = blockIdx.x * 4 + (threadIdx.x >> 6);
  const int beg = rowptr[n], end = rowptr[n + 1];
  float acc = 0.0f;
  int j = beg;
  for (; j + 4 <= end; j += 4) {
    int s0 = csr[j], s1 = csr[j + 1], s2 = csr[j + 2], s3 = csr[j + 3];
    float f0 = bf_lo((unsigned int)f16[(long)s0 * 64 + lane]);
    float f1 = bf_lo((unsigned int)f16[(long)s1 * 64 + lane]);
    float f2 = bf_lo((unsigned int)f16[(long)s2 * 64 + lane]);
    float f3 = bf_lo((unsigned int)f16[(long)s3 * 64 + lane]);
    acc += f0; acc += f1; acc += f2; acc += f3;
  }
  for (; j < end; ++j) acc += bf_lo((unsigned int)f16[(long)csr[j] * 64 + lane]);
  out16[(long)n * 64 + lane] = f2bf(acc * inv[n]);
}

// ---------------- gather aggregation D=128 v2: 4 nodes/wave, 16B/lane ----------------
__global__ __launch_bounds__(256) void k_agg128(const int* __restrict__ rowptr,
                                                const int* __restrict__ csr,
                                                const unsigned short* __restrict__ f16,
                                                const float* __restrict__ inv,
                                                unsigned short* __restrict__ out16) {
  const int lane = threadIdx.x & 63;
  const int wv = threadIdx.x >> 6;   // wave 0..3
  const int g = lane >> 4;           // node group 0..3
  const int q = lane & 15;           // lane in group
  const int n = (blockIdx.x * 4 + wv) * 4 + g;  // grid exact: 6250*16 = 100000
  const int beg = rowptr[n], end = rowptr[n + 1];
  float acc[8] = {0, 0, 0, 0, 0, 0, 0, 0};
  int j = beg;
  for (; j + 2 <= end; j += 2) {
    int s0 = csr[j], s1 = csr[j + 1];
    bf16x8 v0 = *(const bf16x8*)(f16 + (long)s0 * 128 + q * 8);
    bf16x8 v1 = *(const bf16x8*)(f16 + (long)s1 * 128 + q * 8);
#pragma unroll
    for (int i = 0; i < 8; ++i) acc[i] += bfs(v0[i]);
#pragma unroll
    for (int i = 0; i < 8; ++i) acc[i] += bfs(v1[i]);
  }
  if (j < end) {
    bf16x8 v0 = *(const bf16x8*)(f16 + (long)csr[j] * 128 + q * 8);
#pragma unroll
    for (int i = 0; i < 8; ++i) acc[i] += bfs(v0[i]);
  }
  float iv = inv[n];
  bf16x8 r;
#pragma unroll
  for (int i = 0; i < 8; ++i) r[i] = (short)f2bf(acc[i] * iv);
  *(bf16x8*)(out16 + (long)n * 128 + q * 8) = r;
}

// ---------------- MFMA layer 1 ----------------
__global__ __launch_bounds__(256) void k_l1(
    const unsigned short* __restrict__ m1, const unsigned short* __restrict__ x16,
    const unsigned short* __restrict__ w1lt, const unsigned short* __restrict__ w1rt,
    const float* __restrict__ b1l, unsigned short* __restrict__ h16) {
  const int l = threadIdx.x & 63;
  const int w = threadIdx.x >> 6;
  const int cl = l & 15;
  const int kh = l >> 4;
  const int wrow0 = blockIdx.x * 128 + w * 32;
  int ar0 = wrow0 + cl;      if (ar0 >= N_NODES) ar0 = N_NODES - 1;
  int ar1 = wrow0 + 16 + cl; if (ar1 >= N_NODES) ar1 = N_NODES - 1;

  f32x4 acc[2][8];
#pragma unroll
  for (int t = 0; t < 2; ++t)
#pragma unroll
    for (int nt = 0; nt < 8; ++nt) acc[t][nt] = (f32x4){0.f, 0.f, 0.f, 0.f};

#pragma unroll
  for (int s = 0; s < 2; ++s) {
    const int ko = s * 32 + kh * 8;
    bf16x8 am0 = *(const bf16x8*)(m1 + (long)ar0 * 64 + ko);
    bf16x8 ax0 = *(const bf16x8*)(x16 + (long)ar0 * 64 + ko);
    bf16x8 am1 = *(const bf16x8*)(m1 + (long)ar1 * 64 + ko);
    bf16x8 ax1 = *(const bf16x8*)(x16 + (long)ar1 * 64 + ko);
#pragma unroll
    for (int nt = 0; nt < 8; ++nt) {
      bf16x8 bl = *(const bf16x8*)(w1lt + (long)(nt * 16 + cl) * 64 + ko);
      bf16x8 br = *(const bf16x8*)(w1rt + (long)(nt * 16 + cl) * 64 + ko);
      acc[0][nt] = __builtin_amdgcn_mfma_f32_16x16x32_bf16(am0, bl, acc[0][nt], 0, 0, 0);
      acc[0][nt] = __builtin_amdgcn_mfma_f32_16x16x32_bf16(ax0, br, acc[0][nt], 0, 0, 0);
      acc[1][nt] = __builtin_amdgcn_mfma_f32_16x16x32_bf16(am1, bl, acc[1][nt], 0, 0, 0);
      acc[1][nt] = __builtin_amdgcn_mfma_f32_16x16x32_bf16(ax1, br, acc[1][nt], 0, 0, 0);
    }
  }

#pragma unroll
  for (int t = 0; t < 2; ++t)
#pragma unroll
    for (int nt = 0; nt < 8; ++nt) {
      float b = b1l[nt * 16 + cl];
#pragma unroll
      for (int i = 0; i < 4; ++i) {
        int r = wrow0 + t * 16 + kh * 4 + i;
        if (r < N_NODES)
          h16[(long)r * 128 + nt * 16 + cl] = f2bf(fmaxf(acc[t][nt][i] + b, 0.0f));
      }
    }
}

// ---------------- MFMA fused layer 2 + u/v — v4: column-split wave pairing ----------------
// Block = 2 waves sharing 32 rows (grid 3125, exact). Phase 1: wave w computes
// z cols [w*64,(w+1)*64) — same 2-MFMA-per-B-load reuse as before, half the
// per-wave work. Barrier. Phase 2: wave0 -> u (dw1t rows 0..127), wave1 -> v
// (rows 128..255). 2x wave count (6250, ~6/SIMD) at constant per-load reuse.
__global__ __launch_bounds__(128) void k_l2uv(
    const unsigned short* __restrict__ m2, const unsigned short* __restrict__ h16,
    const unsigned short* __restrict__ w2lt, const unsigned short* __restrict__ w2rt,
    const float* __restrict__ b2l, const unsigned short* __restrict__ dw1t,
    const float* __restrict__ db1,
    unsigned short* __restrict__ u16, unsigned short* __restrict__ v16) {
  __shared__ unsigned short s_z[32 * 128];  // 8 KB per block, XOR-swizzled
  char* zb = (char*)s_z;
  const int l = threadIdx.x & 63;
  const int w = threadIdx.x >> 6;  // wave 0/1
  const int cl = l & 15;
  const int kh = l >> 4;
  const int row0 = blockIdx.x * 32;  // grid 3125 exact: no tail
  const int ar0 = row0 + cl;
  const int ar1 = row0 + 16 + cl;

  // ---- phase 1: z cols [w*64, w*64+64) ----
  f32x4 acc[2][4];
#pragma unroll
  for (int t = 0; t < 2; ++t)
#pragma unroll
    for (int nt = 0; nt < 4; ++nt) acc[t][nt] = (f32x4){0.f, 0.f, 0.f, 0.f};

#pragma unroll
  for (int s = 0; s < 4; ++s) {
    const int ko = s * 32 + kh * 8;
    bf16x8 am0 = *(const bf16x8*)(m2 + (long)ar0 * 128 + ko);
    bf16x8 ah0 = *(const bf16x8*)(h16 + (long)ar0 * 128 + ko);
    bf16x8 am1 = *(const bf16x8*)(m2 + (long)ar1 * 128 + ko);
    bf16x8 ah1 = *(const bf16x8*)(h16 + (long)ar1 * 128 + ko);
#pragma unroll
    for (int nt4 = 0; nt4 < 4; ++nt4) {
      const int nt = w * 4 + nt4;
      bf16x8 bl = *(const bf16x8*)(w2lt + (long)(nt * 16 + cl) * 128 + ko);
      bf16x8 br = *(const bf16x8*)(w2rt + (long)(nt * 16 + cl) * 128 + ko);
      acc[0][nt4] = __builtin_amdgcn_mfma_f32_16x16x32_bf16(am0, bl, acc[0][nt4], 0, 0, 0);
      acc[0][nt4] = __builtin_amdgcn_mfma_f32_16x16x32_bf16(ah0, br, acc[0][nt4], 0, 0, 0);
      acc[1][nt4] = __builtin_amdgcn_mfma_f32_16x16x32_bf16(am1, bl, acc[1][nt4], 0, 0, 0);
      acc[1][nt4] = __builtin_amdgcn_mfma_f32_16x16x32_bf16(ah1, br, acc[1][nt4], 0, 0, 0);
    }
  }

  // z (+bias) -> shared LDS (rows 0..31), swizzle byte ^= (row&7)<<4
#pragma unroll
  for (int t = 0; t < 2; ++t)
#pragma unroll
    for (int nt4 = 0; nt4 < 4; ++nt4) {
      const int nt = w * 4 + nt4;
      float b = b2l[nt * 16 + cl];
#pragma unroll
      for (int i = 0; i < 4; ++i) {
        int zr = t * 16 + kh * 4 + i;
        int byte = (zr * 256 + (nt * 16 + cl) * 2) ^ ((zr & 7) << 4);
        *(unsigned short*)(zb + byte) = f2bf(acc[t][nt4][i] + b);
      }
    }
  __syncthreads();

  // ---- phase 2: wave0 -> u (+db1), wave1 -> v ----
  const int bofs = w * 128;  // dw1t row block: u rows 0..127, v rows 128..255
  f32x4 uu[2][8];
#pragma unroll
  for (int t = 0; t < 2; ++t)
#pragma unroll
    for (int nt = 0; nt < 8; ++nt) uu[t][nt] = (f32x4){0.f, 0.f, 0.f, 0.f};
#pragma unroll
  for (int s = 0; s < 4; ++s) {
    const int zr0 = cl;
    const int zr1 = 16 + cl;
    bf16x8 az0 = *(const bf16x8*)(zb + ((zr0 * 256 + s * 64 + kh * 16) ^ ((zr0 & 7) << 4)));
    bf16x8 az1 = *(const bf16x8*)(zb + ((zr1 * 256 + s * 64 + kh * 16) ^ ((zr1 & 7) << 4)));
#pragma unroll
    for (int nt = 0; nt < 8; ++nt) {
      bf16x8 bw = *(const bf16x8*)(dw1t + (long)(bofs + nt * 16 + cl) * 128 + s * 32 + kh * 8);
      uu[0][nt] = __builtin_amdgcn_mfma_f32_16x16x32_bf16(az0, bw, uu[0][nt], 0, 0, 0);
      uu[1][nt] = __builtin_amdgcn_mfma_f32_16x16x32_bf16(az1, bw, uu[1][nt], 0, 0, 0);
    }
  }

  unsigned short* outp = w ? v16 : u16;
#pragma unroll
  for (int t = 0; t < 2; ++t)
#pragma unroll
    for (int nt = 0; nt < 8; ++nt) {
      float bb = w ? 0.0f : db1[nt * 16 + cl];
#pragma unroll
      for (int i = 0; i < 4; ++i) {
        int r = row0 + t * 16 + kh * 4 + i;
        outp[(long)r * 128 + nt * 16 + cl] = f2bf(uu[t][nt][i] + bb);
      }
    }
}

// ---------------- per-label-edge decoder: bucketed, 16 lanes/edge ----------------
__global__ __launch_bounds__(256) void k_edge2(
    const int* __restrict__ lblcnt, const int2* __restrict__ lbin,
    const unsigned short* __restrict__ u16, const unsigned short* __restrict__ v16,
    const float* __restrict__ dw2, const float* __restrict__ db2,
    float* __restrict__ out) {
  const int lane = threadIdx.x & 63;
  const int wv = threadIdx.x >> 6;  // 0..3
  const int g = lane >> 4;          // edge slot within wave: 0..3
  const int q = lane & 15;
  const int b = blockIdx.x / (LCAP / 16);          // bucket
  const int chunk = blockIdx.x % (LCAP / 16);      // chunks of 16 slots
  const int idx = chunk * 16 + wv * 4 + g;
  if (idx >= lblcnt[b]) return;
  int2 rec = lbin[(long)b * LCAP + idx];
  int d = rec.x;
  int s = (b << 9) + (rec.y & 511);
  int e = rec.y >> 9;

  bf16x8 uu = *(const bf16x8*)(u16 + (long)s * 128 + q * 8);
  bf16x8 vv = *(const bf16x8*)(v16 + (long)d * 128 + q * 8);
  float4 w0 = *(const float4*)&dw2[q * 8];
  float4 w1 = *(const float4*)&dw2[q * 8 + 4];
  float w8[8] = {w0.x, w0.y, w0.z, w0.w, w1.x, w1.y, w1.z, w1.w};
  float sum = 0.0f;
#pragma unroll
  for (int i = 0; i < 8; ++i) {
    float h = fmaxf(bfs(uu[i]) + bfs(vv[i]), 0.0f);
    sum = fmaf(h, w8[i], sum);
  }
  sum += __shfl_xor(sum, 1);
  sum += __shfl_xor(sum, 2);
  sum += __shfl_xor(sum, 4);
  sum += __shfl_xor(sum, 8);
  if (q == 0) out[e] = sum + db2[0];
}

extern "C" void kernel_launch(void* const* d_in, const int* in_sizes, int n_in,
                              void* d_out, int out_size, void* d_ws, size_t ws_size,
                              hipStream_t stream) {
  const float* x   = (const float*)d_in[0];
  const int*   ei  = (const int*)d_in[1];
  const int*   eli = (const int*)d_in[2];
  const float* w1l = (const float*)d_in[3];
  const float* b1l = (const float*)d_in[4];
  const float* w1r = (const float*)d_in[5];
  const float* w2l = (const float*)d_in[6];
  const float* b2l = (const float*)d_in[7];
  const float* w2r = (const float*)d_in[8];
  const float* dw1 = (const float*)d_in[9];
  const float* db1 = (const float*)d_in[10];
  const float* dw2 = (const float*)d_in[11];
  const float* db2 = (const float*)d_in[12];
  float* out = (float*)d_out;

  // ---- workspace layout (byte offsets, 16B aligned) ----
  char* wsb = (char*)d_ws;
  float* inv     = (float*)(wsb + 0);              // 400000
  int*   deg_i   = (int*)(wsb + 400000);           // 400000
  int*   rowptr  = (int*)(wsb + 800000);           // 400032
  int*   gcursor = (int*)(wsb + 1200032);          // 1024
  int*   csr     = (int*)(wsb + 1201056);          // 6400000
  int*   binned  = (int*)(wsb + 7601056);          // 6400000
  unsigned short* x16  = (unsigned short*)(wsb + 14001056);   // 12.8 MB
  unsigned short* m1   = (unsigned short*)(wsb + 26801056);   // 12.8 MB
  unsigned short* u16  = (unsigned short*)(wsb + 14001056);   // 25.6 MB (aliases x16+m1)
  unsigned short* h16  = (unsigned short*)(wsb + 39601056);   // 25.6 MB
  unsigned short* m2   = (unsigned short*)(wsb + 65201056);   // 25.6 MB
  unsigned short* v16  = (unsigned short*)(wsb + 90801056);   // 25.6 MB
  unsigned short* w1lt = (unsigned short*)(wsb + 116401056);  // 16384
  unsigned short* w1rt = (unsigned short*)(wsb + 116417440);  // 16384
  unsigned short* w2lt = (unsigned short*)(wsb + 116433824);  // 32768
  unsigned short* w2rt = (unsigned short*)(wsb + 116466592);  // 32768
  unsigned short* dw1t = (unsigned short*)(wsb + 116499360);  // 65536
  int*   bsum    = (int*)(wsb + 116564896);        // 512
  int*   lblcnt  = (int*)(wsb + 116565408);        // 800 (196 used, pad)
  int2*  lbin    = (int2*)(wsb + 116566208);       // 196*3072*8 = 4816896 -> ends ~121.4 MB

  const int* srcp = ei;
  const int* dstp = ei + N_EDGES;
  const int* lsp  = eli;
  const int* ldp  = eli + N_LBL;

  // ---- CSR build + label-edge binning + prep ----
  hipMemsetAsync(deg_i, 0, N_NODES * sizeof(int), stream);
  hipMemsetAsync(lblcnt, 0, NBUCK * sizeof(int), stream);
  k_deg<<<N_EDGES / 256, 256, 0, stream>>>(dstp, deg_i);
  k_scan_a<<<NSCANB, 1024, 0, stream>>>(deg_i, rowptr, inv, bsum);
  k_scan_b<<<1, 128, 0, stream>>>(bsum, rowptr);
  k_scan_c<<<NSCANB, 1024, 0, stream>>>(rowptr, bsum, gcursor);
  k_bin<<<(N_EDGES + 4095) / 4096, 256, 0, stream>>>(srcp, dstp, gcursor, binned);
  k_fill2<<<NBUCK, 256, 0, stream>>>(rowptr, binned, csr);
  k_lbl_bin<<<(N_LBL + 4095) / 4096, 256, 0, stream>>>(lsp, ldp, lblcnt, lbin);
  k_prep<<<(1681920 + 255) / 256, 256, 0, stream>>>(
      x, w1l, w1r, w2l, w2r, dw1, x16, w1lt, w1rt, w2lt, w2rt, dw1t);

  // ---- layer 1 (MFMA) ----
  k_agg64<<<N_NODES / 4, 256, 0, stream>>>(rowptr, csr, x16, inv, m1);
  k_l1<<<(N_NODES + 127) / 128, 256, 0, stream>>>(m1, x16, w1lt, w1rt, b1l, h16);

  // ---- layer 2 + u/v (MFMA v4: column-split wave pairing) ----
  k_agg128<<<N_NODES / 16, 256, 0, stream>>>(rowptr, csr, h16, inv, m2);
  k_l2uv<<<N_NODES / 32, 128, 0, stream>>>(m2, h16, w2lt, w2rt, b2l, dw1t, db1, u16, v16);

  // ---- decoder edge MLP (bucketed) ----
  k_edge2<<<NBUCK * (LCAP / 16), 256, 0, stream>>>(lblcnt, lbin, u16, v16, dw2, db2, out);
}

// Round 18
// 444.855 us; speedup vs baseline: 1.0062x; 1.0062x over previous
//
#include <hip/hip_runtime.h>

#define N_NODES 100000
#define D_IN 64
#define HID 128
#define N_EDGES 1600000
#define N_LBL 500000
#define NBUCK 196   // ceil(100000/512) buckets of 512 dst nodes
#define NSCANB 98   // ceil(100000/1024) scan blocks
#define LCAP 3072   // label-edge bucket capacity (lambda=2560, sigma~51)

typedef __attribute__((ext_vector_type(8))) short bf16x8;
typedef __attribute__((ext_vector_type(4))) float f32x4;

// ---- bf16 helpers (RNE) ----
__device__ inline unsigned short f2bf(float f) {
  unsigned int u = __float_as_uint(f);
  return (unsigned short)((u + 0x7FFFu + ((u >> 16) & 1u)) >> 16);
}
__device__ inline float bf_lo(unsigned int w) { return __uint_as_float(w << 16); }
__device__ inline float bf_hi(unsigned int w) { return __uint_as_float(w & 0xFFFF0000u); }
__device__ inline float bfs(short s) {
  return __uint_as_float(((unsigned int)(unsigned short)s) << 16);
}

// ---------------- degree histogram (int) ----------------
__global__ __launch_bounds__(256) void k_deg(const int* __restrict__ dst,
                                             int* __restrict__ deg) {
  int e = blockIdx.x * 256 + threadIdx.x;
  if (e < N_EDGES) atomicAdd(&deg[dst[e]], 1);
}

// ---------------- scan phase A ----------------
__global__ __launch_bounds__(1024) void k_scan_a(const int* __restrict__ deg,
                                                 int* __restrict__ rowptr,
                                                 float* __restrict__ inv,
                                                 int* __restrict__ bsum) {
  __shared__ int s_wsum[16];
  const int lane = threadIdx.x & 63;
  const int wid = threadIdx.x >> 6;
  const int i = blockIdx.x * 1024 + threadIdx.x;
  int v = (i < N_NODES) ? deg[i] : 0;
  int x = v;
#pragma unroll
  for (int off = 1; off < 64; off <<= 1) {
    int t = __shfl_up(x, off);
    if (lane >= off) x += t;
  }
  if (lane == 63) s_wsum[wid] = x;
  __syncthreads();
  if (wid == 0 && lane < 16) {
    int ws = s_wsum[lane];
    int y = ws;
#pragma unroll
    for (int off = 1; off < 16; off <<= 1) {
      int t = __shfl_up(y, off);
      if (lane >= off) y += t;
    }
    s_wsum[lane] = y - ws;
    if (lane == 15) bsum[blockIdx.x] = y;
  }
  __syncthreads();
  if (i < N_NODES) {
    rowptr[i] = s_wsum[wid] + x - v;
    inv[i] = v > 0 ? 1.0f / (float)v : 0.0f;
  }
}

// ---------------- scan phase B ----------------
__global__ __launch_bounds__(128) void k_scan_b(int* __restrict__ bsum,
                                                int* __restrict__ rowptr) {
  __shared__ int s_w;
  const int tid = threadIdx.x;
  const int lane = tid & 63, wid = tid >> 6;
  int v = (tid < NSCANB) ? bsum[tid] : 0;
  int x = v;
#pragma unroll
  for (int off = 1; off < 64; off <<= 1) {
    int t = __shfl_up(x, off);
    if (lane >= off) x += t;
  }
  if (wid == 0 && lane == 63) s_w = x;
  __syncthreads();
  int incl = x + (wid == 1 ? s_w : 0);
  if (tid < NSCANB) bsum[tid] = incl - v;
  if (tid == NSCANB - 1) rowptr[N_NODES] = incl;
}

// ---------------- scan phase C ----------------
__global__ __launch_bounds__(1024) void k_scan_c(int* __restrict__ rowptr,
                                                 const int* __restrict__ bsum,
                                                 int* __restrict__ gcursor) {
  const int i = blockIdx.x * 1024 + threadIdx.x;
  if (i < N_NODES) {
    int r = rowptr[i] + bsum[blockIdx.x];
    rowptr[i] = r;
    if ((i & 511) == 0) gcursor[i >> 9] = r;
  }
}

// ---------------- bin graph edges by dst bucket ----------------
__global__ __launch_bounds__(256) void k_bin(const int* __restrict__ src,
                                             const int* __restrict__ dst,
                                             int* __restrict__ gcursor,
                                             int* __restrict__ binned) {
  __shared__ int hist[NBUCK];
  __shared__ int base[NBUCK];
  const int tid = threadIdx.x;
  const int e0 = blockIdx.x * 4096 + tid;
  for (int t = tid; t < NBUCK; t += 256) hist[t] = 0;
  __syncthreads();

  int w[16], bk[16], rk[16];
#pragma unroll
  for (int i = 0; i < 16; ++i) {
    int e = e0 + i * 256;
    if (e < N_EDGES) {
      int s = src[e], d = dst[e];
      bk[i] = d >> 9;
      w[i] = (s << 9) | (d & 511);
      rk[i] = atomicAdd(&hist[bk[i]], 1);
    } else {
      bk[i] = -1;
    }
  }
  __syncthreads();
  for (int t = tid; t < NBUCK; t += 256)
    base[t] = hist[t] > 0 ? atomicAdd(&gcursor[t], hist[t]) : 0;
  __syncthreads();
#pragma unroll
  for (int i = 0; i < 16; ++i)
    if (bk[i] >= 0) binned[base[bk[i]] + rk[i]] = w[i];
}

// ---------------- CSR fill from binned edges ----------------
__global__ __launch_bounds__(256) void k_fill2(const int* __restrict__ rowptr,
                                               const int* __restrict__ binned,
                                               int* __restrict__ csr) {
  __shared__ int lcur[512];
  const int b = blockIdx.x;
  const int nb = b << 9;
  const int nn = min(512, N_NODES - nb);
  for (int i = threadIdx.x; i < nn; i += 256) lcur[i] = rowptr[nb + i];
  __syncthreads();
  const int beg = rowptr[nb], end = rowptr[nb + nn];
  for (int e = beg + threadIdx.x; e < end; e += 256) {
    int w = binned[e];
    int pos = atomicAdd(&lcur[w & 511], 1);
    csr[pos] = w >> 9;
  }
}

// ---------------- bin label edges by src bucket (fixed-capacity regions) ----------------
__global__ __launch_bounds__(256) void k_lbl_bin(const int* __restrict__ ls,
                                                 const int* __restrict__ ld,
                                                 int* __restrict__ lblcnt,
                                                 int2* __restrict__ lbin) {
  __shared__ int hist[NBUCK];
  __shared__ int base[NBUCK];
  const int tid = threadIdx.x;
  const int e0 = blockIdx.x * 4096 + tid;
  for (int t = tid; t < NBUCK; t += 256) hist[t] = 0;
  __syncthreads();

  int dd[16], pk[16], bk[16], rk[16];
#pragma unroll
  for (int i = 0; i < 16; ++i) {
    int e = e0 + i * 256;
    if (e < N_LBL) {
      int s = ls[e];
      dd[i] = ld[e];
      bk[i] = s >> 9;
      pk[i] = (e << 9) | (s & 511);
      rk[i] = atomicAdd(&hist[bk[i]], 1);
    } else {
      bk[i] = -1;
    }
  }
  __syncthreads();
  for (int t = tid; t < NBUCK; t += 256)
    base[t] = hist[t] > 0 ? atomicAdd(&lblcnt[t], hist[t]) : 0;
  __syncthreads();
#pragma unroll
  for (int i = 0; i < 16; ++i)
    if (bk[i] >= 0) {
      int2 rec = {dd[i], pk[i]};
      lbin[(long)bk[i] * LCAP + base[bk[i]] + rk[i]] = rec;
    }
}

// ---------------- prep: x -> bf16; w1l,w1r -> bf16 transposed [n][k] ----------------
// threads: 1.6M (x16, 4 f/thr) + 8192 + 8192 = 1616384
__global__ __launch_bounds__(256) void k_prep(
    const float* __restrict__ x, const float* __restrict__ w1l,
    const float* __restrict__ w1r,
    unsigned short* __restrict__ x16, unsigned short* __restrict__ w1lt,
    unsigned short* __restrict__ w1rt) {
  long gid = (long)blockIdx.x * 256 + threadIdx.x;
  if (gid < 1600000) {
    long i = gid * 4;
    float4 v = *(const float4*)&x[i];
    ushort4 q = {f2bf(v.x), f2bf(v.y), f2bf(v.z), f2bf(v.w)};
    *(ushort4*)&x16[i] = q;
    return;
  }
  long idx = gid - 1600000;
  if (idx < 8192) { int n = idx >> 6, k = idx & 63; w1lt[idx] = f2bf(w1l[k * 128 + n]); return; }
  idx -= 8192;
  if (idx < 8192) { int n = idx >> 6, k = idx & 63; w1rt[idx] = f2bf(w1r[k * 128 + n]); }
}

// ---------------- prep composite decoder weights ----------------
// Wt[mat][n][k] (bf16, 4x 128x128): mat0 = w2l@dw1u, mat1 = w2r@dw1u,
// mat2 = w2l@dw1v, mat3 = w2r@dw1v  (dw1u = dw1 rows 0..127, dw1v = rows 128..255).
// buv[0..127] = b2l@dw1u + db1 ; buv[128..255] = b2l@dw1v.
// Within a wave: k wave-uniform (scalar w load), n per-lane (coalesced dw1 load).
__global__ __launch_bounds__(256) void k_prepw(
    const float* __restrict__ w2l, const float* __restrict__ w2r,
    const float* __restrict__ dw1, const float* __restrict__ b2l,
    const float* __restrict__ db1,
    unsigned short* __restrict__ Wt, float* __restrict__ buv) {
  int idx = blockIdx.x * 256 + threadIdx.x;
  if (idx < 65536) {
    int mat = idx >> 14;
    int rem = idx & 16383;
    int k = rem >> 7;
    int n = rem & 127;
    const float* w = (mat & 1) ? w2r : w2l;
    const float* d = dw1 + (mat >> 1) * (128 * 128);
    float acc = 0.f;
#pragma unroll 8
    for (int j = 0; j < 128; ++j) acc = fmaf(w[k * 128 + j], d[j * 128 + n], acc);
    Wt[(long)mat * 16384 + n * 128 + k] = f2bf(acc);
  } else if (idx < 65792) {
    int t = idx - 65536;
    int n = t & 127;
    const float* d = dw1 + (t >> 7) * (128 * 128);
    float acc = (t < 128) ? db1[n] : 0.f;
#pragma unroll 8
    for (int j = 0; j < 128; ++j) acc = fmaf(b2l[j], d[j * 128 + n], acc);
    buv[t] = acc;
  }
}

// ---------------- gather aggregation D=64 (bf16 in/out) ----------------
__global__ __launch_bounds__(256) void k_agg64(const int* __restrict__ rowptr,
                                               const int* __restrict__ csr,
                                               const unsigned short* __restrict__ f16,
                                               const float* __restrict__ inv,
                                               unsigned short* __restrict__ out16) {
  const int lane = threadIdx.x & 63;
  const int n = blockIdx.x * 4 + (threadIdx.x >> 6);
  const int beg = rowptr[n], end = rowptr[n + 1];
  float acc = 0.0f;
  int j = beg;
  for (; j + 4 <= end; j += 4) {
    int s0 = csr[j], s1 = csr[j + 1], s2 = csr[j + 2], s3 = csr[j + 3];
    float f0 = bf_lo((unsigned int)f16[(long)s0 * 64 + lane]);
    float f1 = bf_lo((unsigned int)f16[(long)s1 * 64 + lane]);
    float f2 = bf_lo((unsigned int)f16[(long)s2 * 64 + lane]);
    float f3 = bf_lo((unsigned int)f16[(long)s3 * 64 + lane]);
    acc += f0; acc += f1; acc += f2; acc += f3;
  }
  for (; j < end; ++j) acc += bf_lo((unsigned int)f16[(long)csr[j] * 64 + lane]);
  out16[(long)n * 64 + lane] = f2bf(acc * inv[n]);
}

// ---------------- gather aggregation D=128 v2: 4 nodes/wave, 16B/lane ----------------
__global__ __launch_bounds__(256) void k_agg128(const int* __restrict__ rowptr,
                                                const int* __restrict__ csr,
                                                const unsigned short* __restrict__ f16,
                                                const float* __restrict__ inv,
                                                unsigned short* __restrict__ out16) {
  const int lane = threadIdx.x & 63;
  const int wv = threadIdx.x >> 6;   // wave 0..3
  const int g = lane >> 4;           // node group 0..3
  const int q = lane & 15;           // lane in group
  const int n = (blockIdx.x * 4 + wv) * 4 + g;  // grid exact: 6250*16 = 100000
  const int beg = rowptr[n], end = rowptr[n + 1];
  float acc[8] = {0, 0, 0, 0, 0, 0, 0, 0};
  int j = beg;
  for (; j + 2 <= end; j += 2) {
    int s0 = csr[j], s1 = csr[j + 1];
    bf16x8 v0 = *(const bf16x8*)(f16 + (long)s0 * 128 + q * 8);
    bf16x8 v1 = *(const bf16x8*)(f16 + (long)s1 * 128 + q * 8);
#pragma unroll
    for (int i = 0; i < 8; ++i) acc[i] += bfs(v0[i]);
#pragma unroll
    for (int i = 0; i < 8; ++i) acc[i] += bfs(v1[i]);
  }
  if (j < end) {
    bf16x8 v0 = *(const bf16x8*)(f16 + (long)csr[j] * 128 + q * 8);
#pragma unroll
    for (int i = 0; i < 8; ++i) acc[i] += bfs(v0[i]);
  }
  float iv = inv[n];
  bf16x8 r;
#pragma unroll
  for (int i = 0; i < 8; ++i) r[i] = (short)f2bf(acc[i] * iv);
  *(bf16x8*)(out16 + (long)n * 128 + q * 8) = r;
}

// ---------------- MFMA layer 1 ----------------
__global__ __launch_bounds__(256) void k_l1(
    const unsigned short* __restrict__ m1, const unsigned short* __restrict__ x16,
    const unsigned short* __restrict__ w1lt, const unsigned short* __restrict__ w1rt,
    const float* __restrict__ b1l, unsigned short* __restrict__ h16) {
  const int l = threadIdx.x & 63;
  const int w = threadIdx.x >> 6;
  const int cl = l & 15;
  const int kh = l >> 4;
  const int wrow0 = blockIdx.x * 128 + w * 32;
  int ar0 = wrow0 + cl;      if (ar0 >= N_NODES) ar0 = N_NODES - 1;
  int ar1 = wrow0 + 16 + cl; if (ar1 >= N_NODES) ar1 = N_NODES - 1;

  f32x4 acc[2][8];
#pragma unroll
  for (int t = 0; t < 2; ++t)
#pragma unroll
    for (int nt = 0; nt < 8; ++nt) acc[t][nt] = (f32x4){0.f, 0.f, 0.f, 0.f};

#pragma unroll
  for (int s = 0; s < 2; ++s) {
    const int ko = s * 32 + kh * 8;
    bf16x8 am0 = *(const bf16x8*)(m1 + (long)ar0 * 64 + ko);
    bf16x8 ax0 = *(const bf16x8*)(x16 + (long)ar0 * 64 + ko);
    bf16x8 am1 = *(const bf16x8*)(m1 + (long)ar1 * 64 + ko);
    bf16x8 ax1 = *(const bf16x8*)(x16 + (long)ar1 * 64 + ko);
#pragma unroll
    for (int nt = 0; nt < 8; ++nt) {
      bf16x8 bl = *(const bf16x8*)(w1lt + (long)(nt * 16 + cl) * 64 + ko);
      bf16x8 br = *(const bf16x8*)(w1rt + (long)(nt * 16 + cl) * 64 + ko);
      acc[0][nt] = __builtin_amdgcn_mfma_f32_16x16x32_bf16(am0, bl, acc[0][nt], 0, 0, 0);
      acc[0][nt] = __builtin_amdgcn_mfma_f32_16x16x32_bf16(ax0, br, acc[0][nt], 0, 0, 0);
      acc[1][nt] = __builtin_amdgcn_mfma_f32_16x16x32_bf16(am1, bl, acc[1][nt], 0, 0, 0);
      acc[1][nt] = __builtin_amdgcn_mfma_f32_16x16x32_bf16(ax1, br, acc[1][nt], 0, 0, 0);
    }
  }

#pragma unroll
  for (int t = 0; t < 2; ++t)
#pragma unroll
    for (int nt = 0; nt < 8; ++nt) {
      float b = b1l[nt * 16 + cl];
#pragma unroll
      for (int i = 0; i < 4; ++i) {
        int r = wrow0 + t * 16 + kh * 4 + i;
        if (r < N_NODES)
          h16[(long)r * 128 + nt * 16 + cl] = f2bf(fmaxf(acc[t][nt][i] + b, 0.0f));
      }
    }
}

// ---------------- MFMA u/v via composite weights — single phase, no LDS ----------------
// u = m2@Wmu + h@Whu + bu ; v = m2@Wmv + h@Whv + bv (z eliminated algebraically).
// Block = 2 waves on the same 32 rows: wave0 -> u, wave1 -> v. Grid 3125 exact.
// No LDS, no barrier, no z quantization. ~96 VGPR.
__global__ __launch_bounds__(128) void k_uv(
    const unsigned short* __restrict__ m2, const unsigned short* __restrict__ h16,
    const unsigned short* __restrict__ Wt, const float* __restrict__ buv,
    unsigned short* __restrict__ u16, unsigned short* __restrict__ v16) {
  const int l = threadIdx.x & 63;
  const int w = threadIdx.x >> 6;  // 0 -> u, 1 -> v
  const int cl = l & 15;
  const int kh = l >> 4;
  const int row0 = blockIdx.x * 32;  // grid 3125 exact
  const int ar0 = row0 + cl;
  const int ar1 = row0 + 16 + cl;
  const unsigned short* Wm = Wt + (long)(w ? 2 : 0) * 16384;
  const unsigned short* Wh = Wt + (long)(w ? 3 : 1) * 16384;

  f32x4 acc[2][8];
#pragma unroll
  for (int t = 0; t < 2; ++t)
#pragma unroll
    for (int nt = 0; nt < 8; ++nt) acc[t][nt] = (f32x4){0.f, 0.f, 0.f, 0.f};

#pragma unroll
  for (int s = 0; s < 4; ++s) {
    const int ko = s * 32 + kh * 8;
    bf16x8 am0 = *(const bf16x8*)(m2 + (long)ar0 * 128 + ko);
    bf16x8 ah0 = *(const bf16x8*)(h16 + (long)ar0 * 128 + ko);
    bf16x8 am1 = *(const bf16x8*)(m2 + (long)ar1 * 128 + ko);
    bf16x8 ah1 = *(const bf16x8*)(h16 + (long)ar1 * 128 + ko);
#pragma unroll
    for (int nt = 0; nt < 8; ++nt) {
      bf16x8 bm = *(const bf16x8*)(Wm + (long)(nt * 16 + cl) * 128 + ko);
      bf16x8 bh = *(const bf16x8*)(Wh + (long)(nt * 16 + cl) * 128 + ko);
      acc[0][nt] = __builtin_amdgcn_mfma_f32_16x16x32_bf16(am0, bm, acc[0][nt], 0, 0, 0);
      acc[0][nt] = __builtin_amdgcn_mfma_f32_16x16x32_bf16(ah0, bh, acc[0][nt], 0, 0, 0);
      acc[1][nt] = __builtin_amdgcn_mfma_f32_16x16x32_bf16(am1, bm, acc[1][nt], 0, 0, 0);
      acc[1][nt] = __builtin_amdgcn_mfma_f32_16x16x32_bf16(ah1, bh, acc[1][nt], 0, 0, 0);
    }
  }

  unsigned short* outp = w ? v16 : u16;
#pragma unroll
  for (int t = 0; t < 2; ++t)
#pragma unroll
    for (int nt = 0; nt < 8; ++nt) {
      float bb = buv[w * 128 + nt * 16 + cl];
#pragma unroll
      for (int i = 0; i < 4; ++i) {
        int r = row0 + t * 16 + kh * 4 + i;
        outp[(long)r * 128 + nt * 16 + cl] = f2bf(acc[t][nt][i] + bb);
      }
    }
}

// ---------------- per-label-edge decoder: bucketed, 16 lanes/edge ----------------
__global__ __launch_bounds__(256) void k_edge2(
    const int* __restrict__ lblcnt, const int2* __restrict__ lbin,
    const unsigned short* __restrict__ u16, const unsigned short* __restrict__ v16,
    const float* __restrict__ dw2, const float* __restrict__ db2,
    float* __restrict__ out) {
  const int lane = threadIdx.x & 63;
  const int wv = threadIdx.x >> 6;  // 0..3
  const int g = lane >> 4;          // edge slot within wave: 0..3
  const int q = lane & 15;
  const int b = blockIdx.x / (LCAP / 16);          // bucket
  const int chunk = blockIdx.x % (LCAP / 16);      // chunks of 16 slots
  const int idx = chunk * 16 + wv * 4 + g;
  if (idx >= lblcnt[b]) return;
  int2 rec = lbin[(long)b * LCAP + idx];
  int d = rec.x;
  int s = (b << 9) + (rec.y & 511);
  int e = rec.y >> 9;

  bf16x8 uu = *(const bf16x8*)(u16 + (long)s * 128 + q * 8);
  bf16x8 vv = *(const bf16x8*)(v16 + (long)d * 128 + q * 8);
  float4 w0 = *(const float4*)&dw2[q * 8];
  float4 w1 = *(const float4*)&dw2[q * 8 + 4];
  float w8[8] = {w0.x, w0.y, w0.z, w0.w, w1.x, w1.y, w1.z, w1.w};
  float sum = 0.0f;
#pragma unroll
  for (int i = 0; i < 8; ++i) {
    float h = fmaxf(bfs(uu[i]) + bfs(vv[i]), 0.0f);
    sum = fmaf(h, w8[i], sum);
  }
  sum += __shfl_xor(sum, 1);
  sum += __shfl_xor(sum, 2);
  sum += __shfl_xor(sum, 4);
  sum += __shfl_xor(sum, 8);
  if (q == 0) out[e] = sum + db2[0];
}

extern "C" void kernel_launch(void* const* d_in, const int* in_sizes, int n_in,
                              void* d_out, int out_size, void* d_ws, size_t ws_size,
                              hipStream_t stream) {
  const float* x   = (const float*)d_in[0];
  const int*   ei  = (const int*)d_in[1];
  const int*   eli = (const int*)d_in[2];
  const float* w1l = (const float*)d_in[3];
  const float* b1l = (const float*)d_in[4];
  const float* w1r = (const float*)d_in[5];
  const float* w2l = (const float*)d_in[6];
  const float* b2l = (const float*)d_in[7];
  const float* w2r = (const float*)d_in[8];
  const float* dw1 = (const float*)d_in[9];
  const float* db1 = (const float*)d_in[10];
  const float* dw2 = (const float*)d_in[11];
  const float* db2 = (const float*)d_in[12];
  float* out = (float*)d_out;

  // ---- workspace layout (byte offsets, 16B aligned) ----
  char* wsb = (char*)d_ws;
  float* inv     = (float*)(wsb + 0);              // 400000
  int*   deg_i   = (int*)(wsb + 400000);           // 400000
  int*   rowptr  = (int*)(wsb + 800000);           // 400032
  int*   gcursor = (int*)(wsb + 1200032);          // 1024
  int*   csr     = (int*)(wsb + 1201056);          // 6400000
  int*   binned  = (int*)(wsb + 7601056);          // 6400000
  unsigned short* x16  = (unsigned short*)(wsb + 14001056);   // 12.8 MB
  unsigned short* m1   = (unsigned short*)(wsb + 26801056);   // 12.8 MB
  unsigned short* u16  = (unsigned short*)(wsb + 14001056);   // 25.6 MB (aliases x16+m1)
  unsigned short* h16  = (unsigned short*)(wsb + 39601056);   // 25.6 MB
  unsigned short* m2   = (unsigned short*)(wsb + 65201056);   // 25.6 MB
  unsigned short* v16  = (unsigned short*)(wsb + 90801056);   // 25.6 MB
  unsigned short* w1lt = (unsigned short*)(wsb + 116401056);  // 16384
  unsigned short* w1rt = (unsigned short*)(wsb + 116417440);  // 16384
  unsigned short* Wt   = (unsigned short*)(wsb + 116433824);  // 131072 (4x 128x128 bf16)
  float* buv     = (float*)(wsb + 116564896);      // 1024
  int*   bsum    = (int*)(wsb + 116565920);        // 512
  int*   lblcnt  = (int*)(wsb + 116566432);        // 1024 (196 used)
  int2*  lbin    = (int2*)(wsb + 116567456);       // 4816896 -> ends ~121.4 MB

  const int* srcp = ei;
  const int* dstp = ei + N_EDGES;
  const int* lsp  = eli;
  const int* ldp  = eli + N_LBL;

  // ---- CSR build + label-edge binning + prep ----
  hipMemsetAsync(deg_i, 0, N_NODES * sizeof(int), stream);
  hipMemsetAsync(lblcnt, 0, NBUCK * sizeof(int), stream);
  k_deg<<<N_EDGES / 256, 256, 0, stream>>>(dstp, deg_i);
  k_scan_a<<<NSCANB, 1024, 0, stream>>>(deg_i, rowptr, inv, bsum);
  k_scan_b<<<1, 128, 0, stream>>>(bsum, rowptr);
  k_scan_c<<<NSCANB, 1024, 0, stream>>>(rowptr, bsum, gcursor);
  k_bin<<<(N_EDGES + 4095) / 4096, 256, 0, stream>>>(srcp, dstp, gcursor, binned);
  k_fill2<<<NBUCK, 256, 0, stream>>>(rowptr, binned, csr);
  k_lbl_bin<<<(N_LBL + 4095) / 4096, 256, 0, stream>>>(lsp, ldp, lblcnt, lbin);
  k_prep<<<(1616384 + 255) / 256, 256, 0, stream>>>(x, w1l, w1r, x16, w1lt, w1rt);
  k_prepw<<<257, 256, 0, stream>>>(w2l, w2r, dw1, b2l, db1, Wt, buv);

  // ---- layer 1 (MFMA) ----
  k_agg64<<<N_NODES / 4, 256, 0, stream>>>(rowptr, csr, x16, inv, m1);
  k_l1<<<(N_NODES + 127) / 128, 256, 0, stream>>>(m1, x16, w1lt, w1rt, b1l, h16);

  // ---- u/v via composite weights (single-phase MFMA, z eliminated) ----
  k_agg128<<<N_NODES / 16, 256, 0, stream>>>(rowptr, csr, h16, inv, m2);
  k_uv<<<N_NODES / 32, 128, 0, stream>>>(m2, h16, Wt, buv, u16, v16);

  // ---- decoder edge MLP (bucketed) ----
  k_edge2<<<NBUCK * (LCAP / 16), 256, 0, stream>>>(lblcnt, lbin, u16, v16, dw2, db2, out);
}

// Round 19
// 423.128 us; speedup vs baseline: 1.0578x; 1.0513x over previous
//
#include <hip/hip_runtime.h>

#define N_NODES 100000
#define D_IN 64
#define HID 128
#define N_EDGES 1600000
#define N_LBL 500000
#define NBUCK 196   // ceil(100000/512) buckets of 512 dst nodes
#define NSCANB 98   // ceil(100000/1024) scan blocks
#define LCAP 3072   // label-edge bucket capacity (lambda=2560, sigma~51)

typedef __attribute__((ext_vector_type(8))) short bf16x8;
typedef __attribute__((ext_vector_type(4))) float f32x4;

// ---- bf16 helpers (RNE) ----
__device__ inline unsigned short f2bf(float f) {
  unsigned int u = __float_as_uint(f);
  return (unsigned short)((u + 0x7FFFu + ((u >> 16) & 1u)) >> 16);
}
__device__ inline float bf_lo(unsigned int w) { return __uint_as_float(w << 16); }
__device__ inline float bf_hi(unsigned int w) { return __uint_as_float(w & 0xFFFF0000u); }
__device__ inline float bfs(short s) {
  return __uint_as_float(((unsigned int)(unsigned short)s) << 16);
}

// ---------------- degree histogram (int) ----------------
__global__ __launch_bounds__(256) void k_deg(const int* __restrict__ dst,
                                             int* __restrict__ deg) {
  int e = blockIdx.x * 256 + threadIdx.x;
  if (e < N_EDGES) atomicAdd(&deg[dst[e]], 1);
}

// ---------------- scan phase A ----------------
__global__ __launch_bounds__(1024) void k_scan_a(const int* __restrict__ deg,
                                                 int* __restrict__ rowptr,
                                                 float* __restrict__ inv,
                                                 int* __restrict__ bsum) {
  __shared__ int s_wsum[16];
  const int lane = threadIdx.x & 63;
  const int wid = threadIdx.x >> 6;
  const int i = blockIdx.x * 1024 + threadIdx.x;
  int v = (i < N_NODES) ? deg[i] : 0;
  int x = v;
#pragma unroll
  for (int off = 1; off < 64; off <<= 1) {
    int t = __shfl_up(x, off);
    if (lane >= off) x += t;
  }
  if (lane == 63) s_wsum[wid] = x;
  __syncthreads();
  if (wid == 0 && lane < 16) {
    int ws = s_wsum[lane];
    int y = ws;
#pragma unroll
    for (int off = 1; off < 16; off <<= 1) {
      int t = __shfl_up(y, off);
      if (lane >= off) y += t;
    }
    s_wsum[lane] = y - ws;
    if (lane == 15) bsum[blockIdx.x] = y;
  }
  __syncthreads();
  if (i < N_NODES) {
    rowptr[i] = s_wsum[wid] + x - v;
    inv[i] = v > 0 ? 1.0f / (float)v : 0.0f;
  }
}

// ---------------- scan phase B ----------------
__global__ __launch_bounds__(128) void k_scan_b(int* __restrict__ bsum,
                                                int* __restrict__ rowptr) {
  __shared__ int s_w;
  const int tid = threadIdx.x;
  const int lane = tid & 63, wid = tid >> 6;
  int v = (tid < NSCANB) ? bsum[tid] : 0;
  int x = v;
#pragma unroll
  for (int off = 1; off < 64; off <<= 1) {
    int t = __shfl_up(x, off);
    if (lane >= off) x += t;
  }
  if (wid == 0 && lane == 63) s_w = x;
  __syncthreads();
  int incl = x + (wid == 1 ? s_w : 0);
  if (tid < NSCANB) bsum[tid] = incl - v;
  if (tid == NSCANB - 1) rowptr[N_NODES] = incl;
}

// ---------------- scan phase C ----------------
__global__ __launch_bounds__(1024) void k_scan_c(int* __restrict__ rowptr,
                                                 const int* __restrict__ bsum,
                                                 int* __restrict__ gcursor) {
  const int i = blockIdx.x * 1024 + threadIdx.x;
  if (i < N_NODES) {
    int r = rowptr[i] + bsum[blockIdx.x];
    rowptr[i] = r;
    if ((i & 511) == 0) gcursor[i >> 9] = r;
  }
}

// ---------------- bin graph edges by dst bucket ----------------
__global__ __launch_bounds__(256) void k_bin(const int* __restrict__ src,
                                             const int* __restrict__ dst,
                                             int* __restrict__ gcursor,
                                             int* __restrict__ binned) {
  __shared__ int hist[NBUCK];
  __shared__ int base[NBUCK];
  const int tid = threadIdx.x;
  const int e0 = blockIdx.x * 4096 + tid;
  for (int t = tid; t < NBUCK; t += 256) hist[t] = 0;
  __syncthreads();

  int w[16], bk[16], rk[16];
#pragma unroll
  for (int i = 0; i < 16; ++i) {
    int e = e0 + i * 256;
    if (e < N_EDGES) {
      int s = src[e], d = dst[e];
      bk[i] = d >> 9;
      w[i] = (s << 9) | (d & 511);
      rk[i] = atomicAdd(&hist[bk[i]], 1);
    } else {
      bk[i] = -1;
    }
  }
  __syncthreads();
  for (int t = tid; t < NBUCK; t += 256)
    base[t] = hist[t] > 0 ? atomicAdd(&gcursor[t], hist[t]) : 0;
  __syncthreads();
#pragma unroll
  for (int i = 0; i < 16; ++i)
    if (bk[i] >= 0) binned[base[bk[i]] + rk[i]] = w[i];
}

// ---------------- CSR fill from binned edges ----------------
__global__ __launch_bounds__(256) void k_fill2(const int* __restrict__ rowptr,
                                               const int* __restrict__ binned,
                                               int* __restrict__ csr) {
  __shared__ int lcur[512];
  const int b = blockIdx.x;
  const int nb = b << 9;
  const int nn = min(512, N_NODES - nb);
  for (int i = threadIdx.x; i < nn; i += 256) lcur[i] = rowptr[nb + i];
  __syncthreads();
  const int beg = rowptr[nb], end = rowptr[nb + nn];
  for (int e = beg + threadIdx.x; e < end; e += 256) {
    int w = binned[e];
    int pos = atomicAdd(&lcur[w & 511], 1);
    csr[pos] = w >> 9;
  }
}

// ---------------- bin label edges by src bucket (fixed-capacity regions) ----------------
__global__ __launch_bounds__(256) void k_lbl_bin(const int* __restrict__ ls,
                                                 const int* __restrict__ ld,
                                                 int* __restrict__ lblcnt,
                                                 int2* __restrict__ lbin) {
  __shared__ int hist[NBUCK];
  __shared__ int base[NBUCK];
  const int tid = threadIdx.x;
  const int e0 = blockIdx.x * 4096 + tid;
  for (int t = tid; t < NBUCK; t += 256) hist[t] = 0;
  __syncthreads();

  int dd[16], pk[16], bk[16], rk[16];
#pragma unroll
  for (int i = 0; i < 16; ++i) {
    int e = e0 + i * 256;
    if (e < N_LBL) {
      int s = ls[e];
      dd[i] = ld[e];
      bk[i] = s >> 9;
      pk[i] = (e << 9) | (s & 511);
      rk[i] = atomicAdd(&hist[bk[i]], 1);
    } else {
      bk[i] = -1;
    }
  }
  __syncthreads();
  for (int t = tid; t < NBUCK; t += 256)
    base[t] = hist[t] > 0 ? atomicAdd(&lblcnt[t], hist[t]) : 0;
  __syncthreads();
#pragma unroll
  for (int i = 0; i < 16; ++i)
    if (bk[i] >= 0) {
      int2 rec = {dd[i], pk[i]};
      lbin[(long)bk[i] * LCAP + base[bk[i]] + rk[i]] = rec;
    }
}

// ---------------- prep: x -> bf16; w1l,w1r -> bf16 transposed [n][k] ----------------
__global__ __launch_bounds__(256) void k_prep(
    const float* __restrict__ x, const float* __restrict__ w1l,
    const float* __restrict__ w1r,
    unsigned short* __restrict__ x16, unsigned short* __restrict__ w1lt,
    unsigned short* __restrict__ w1rt) {
  long gid = (long)blockIdx.x * 256 + threadIdx.x;
  if (gid < 1600000) {
    long i = gid * 4;
    float4 v = *(const float4*)&x[i];
    ushort4 q = {f2bf(v.x), f2bf(v.y), f2bf(v.z), f2bf(v.w)};
    *(ushort4*)&x16[i] = q;
    return;
  }
  long idx = gid - 1600000;
  if (idx < 8192) { int n = idx >> 6, k = idx & 63; w1lt[idx] = f2bf(w1l[k * 128 + n]); return; }
  idx -= 8192;
  if (idx < 8192) { int n = idx >> 6, k = idx & 63; w1rt[idx] = f2bf(w1r[k * 128 + n]); }
}

// ---------------- prep composite decoder weights ----------------
__global__ __launch_bounds__(256) void k_prepw(
    const float* __restrict__ w2l, const float* __restrict__ w2r,
    const float* __restrict__ dw1, const float* __restrict__ b2l,
    const float* __restrict__ db1,
    unsigned short* __restrict__ Wt, float* __restrict__ buv) {
  int idx = blockIdx.x * 256 + threadIdx.x;
  if (idx < 65536) {
    int mat = idx >> 14;
    int rem = idx & 16383;
    int k = rem >> 7;
    int n = rem & 127;
    const float* w = (mat & 1) ? w2r : w2l;
    const float* d = dw1 + (mat >> 1) * (128 * 128);
    float acc = 0.f;
#pragma unroll 8
    for (int j = 0; j < 128; ++j) acc = fmaf(w[k * 128 + j], d[j * 128 + n], acc);
    Wt[(long)mat * 16384 + n * 128 + k] = f2bf(acc);
  } else if (idx < 65792) {
    int t = idx - 65536;
    int n = t & 127;
    const float* d = dw1 + (t >> 7) * (128 * 128);
    float acc = (t < 128) ? db1[n] : 0.f;
#pragma unroll 8
    for (int j = 0; j < 128; ++j) acc = fmaf(b2l[j], d[j * 128 + n], acc);
    buv[t] = acc;
  }
}

// ---------------- gather aggregation D=64 v2: wave per node, 8 slots x 16B ----------------
__global__ __launch_bounds__(256) void k_agg64(const int* __restrict__ rowptr,
                                               const int* __restrict__ csr,
                                               const unsigned short* __restrict__ f16,
                                               const float* __restrict__ inv,
                                               unsigned short* __restrict__ out16) {
  const int lane = threadIdx.x & 63;
  const int wv = threadIdx.x >> 6;
  const int q = lane & 7;    // 16B slice of the 128B row
  const int g = lane >> 3;   // edge slot 0..7
  const int n = blockIdx.x * 4 + wv;  // grid exact: 25000*4
  const int beg = rowptr[n], end = rowptr[n + 1];
  float acc[8] = {0, 0, 0, 0, 0, 0, 0, 0};
  int j = beg + g;
  for (; j + 8 < end; j += 16) {  // unroll 2: j and j+8 both valid
    int s0 = csr[j], s1 = csr[j + 8];
    bf16x8 v0 = *(const bf16x8*)(f16 + (long)s0 * 64 + q * 8);
    bf16x8 v1 = *(const bf16x8*)(f16 + (long)s1 * 64 + q * 8);
#pragma unroll
    for (int i = 0; i < 8; ++i) acc[i] += bfs(v0[i]);
#pragma unroll
    for (int i = 0; i < 8; ++i) acc[i] += bfs(v1[i]);
  }
  if (j < end) {
    bf16x8 v0 = *(const bf16x8*)(f16 + (long)csr[j] * 64 + q * 8);
#pragma unroll
    for (int i = 0; i < 8; ++i) acc[i] += bfs(v0[i]);
  }
  // reduce across the 8 edge slots (lane bits 3..5)
#pragma unroll
  for (int m = 8; m <= 32; m <<= 1)
#pragma unroll
    for (int i = 0; i < 8; ++i) acc[i] += __shfl_xor(acc[i], m);
  if (g == 0) {
    float iv = inv[n];
    bf16x8 r;
#pragma unroll
    for (int i = 0; i < 8; ++i) r[i] = (short)f2bf(acc[i] * iv);
    *(bf16x8*)(out16 + (long)n * 64 + q * 8) = r;
  }
}

// ---------------- gather aggregation D=128 v3: wave per node, 4 slots x 16 lanes ----------------
// 8 independent row-loads in flight per wave (4 slots x unroll 2); per-node
// dependent chain ~ deg/8; no inter-node imbalance within a wave.
__global__ __launch_bounds__(256) void k_agg128(const int* __restrict__ rowptr,
                                                const int* __restrict__ csr,
                                                const unsigned short* __restrict__ f16,
                                                const float* __restrict__ inv,
                                                unsigned short* __restrict__ out16) {
  const int lane = threadIdx.x & 63;
  const int wv = threadIdx.x >> 6;
  const int q = lane & 15;   // 16B slice of the 256B row
  const int g = lane >> 4;   // edge slot 0..3
  const int n = blockIdx.x * 4 + wv;  // grid exact: 25000*4
  const int beg = rowptr[n], end = rowptr[n + 1];
  float acc[8] = {0, 0, 0, 0, 0, 0, 0, 0};
  int j = beg + g;
  for (; j + 4 < end; j += 8) {  // unroll 2: j and j+4 both valid
    int s0 = csr[j], s1 = csr[j + 4];
    bf16x8 v0 = *(const bf16x8*)(f16 + (long)s0 * 128 + q * 8);
    bf16x8 v1 = *(const bf16x8*)(f16 + (long)s1 * 128 + q * 8);
#pragma unroll
    for (int i = 0; i < 8; ++i) acc[i] += bfs(v0[i]);
#pragma unroll
    for (int i = 0; i < 8; ++i) acc[i] += bfs(v1[i]);
  }
  if (j < end) {
    bf16x8 v0 = *(const bf16x8*)(f16 + (long)csr[j] * 128 + q * 8);
#pragma unroll
    for (int i = 0; i < 8; ++i) acc[i] += bfs(v0[i]);
  }
  // reduce across the 4 edge slots (lane bits 4..5)
#pragma unroll
  for (int m = 16; m <= 32; m <<= 1)
#pragma unroll
    for (int i = 0; i < 8; ++i) acc[i] += __shfl_xor(acc[i], m);
  if (g == 0) {
    float iv = inv[n];
    bf16x8 r;
#pragma unroll
    for (int i = 0; i < 8; ++i) r[i] = (short)f2bf(acc[i] * iv);
    *(bf16x8*)(out16 + (long)n * 128 + q * 8) = r;
  }
}

// ---------------- MFMA layer 1 ----------------
__global__ __launch_bounds__(256) void k_l1(
    const unsigned short* __restrict__ m1, const unsigned short* __restrict__ x16,
    const unsigned short* __restrict__ w1lt, const unsigned short* __restrict__ w1rt,
    const float* __restrict__ b1l, unsigned short* __restrict__ h16) {
  const int l = threadIdx.x & 63;
  const int w = threadIdx.x >> 6;
  const int cl = l & 15;
  const int kh = l >> 4;
  const int wrow0 = blockIdx.x * 128 + w * 32;
  int ar0 = wrow0 + cl;      if (ar0 >= N_NODES) ar0 = N_NODES - 1;
  int ar1 = wrow0 + 16 + cl; if (ar1 >= N_NODES) ar1 = N_NODES - 1;

  f32x4 acc[2][8];
#pragma unroll
  for (int t = 0; t < 2; ++t)
#pragma unroll
    for (int nt = 0; nt < 8; ++nt) acc[t][nt] = (f32x4){0.f, 0.f, 0.f, 0.f};

#pragma unroll
  for (int s = 0; s < 2; ++s) {
    const int ko = s * 32 + kh * 8;
    bf16x8 am0 = *(const bf16x8*)(m1 + (long)ar0 * 64 + ko);
    bf16x8 ax0 = *(const bf16x8*)(x16 + (long)ar0 * 64 + ko);
    bf16x8 am1 = *(const bf16x8*)(m1 + (long)ar1 * 64 + ko);
    bf16x8 ax1 = *(const bf16x8*)(x16 + (long)ar1 * 64 + ko);
#pragma unroll
    for (int nt = 0; nt < 8; ++nt) {
      bf16x8 bl = *(const bf16x8*)(w1lt + (long)(nt * 16 + cl) * 64 + ko);
      bf16x8 br = *(const bf16x8*)(w1rt + (long)(nt * 16 + cl) * 64 + ko);
      acc[0][nt] = __builtin_amdgcn_mfma_f32_16x16x32_bf16(am0, bl, acc[0][nt], 0, 0, 0);
      acc[0][nt] = __builtin_amdgcn_mfma_f32_16x16x32_bf16(ax0, br, acc[0][nt], 0, 0, 0);
      acc[1][nt] = __builtin_amdgcn_mfma_f32_16x16x32_bf16(am1, bl, acc[1][nt], 0, 0, 0);
      acc[1][nt] = __builtin_amdgcn_mfma_f32_16x16x32_bf16(ax1, br, acc[1][nt], 0, 0, 0);
    }
  }

#pragma unroll
  for (int t = 0; t < 2; ++t)
#pragma unroll
    for (int nt = 0; nt < 8; ++nt) {
      float b = b1l[nt * 16 + cl];
#pragma unroll
      for (int i = 0; i < 4; ++i) {
        int r = wrow0 + t * 16 + kh * 4 + i;
        if (r < N_NODES)
          h16[(long)r * 128 + nt * 16 + cl] = f2bf(fmaxf(acc[t][nt][i] + b, 0.0f));
      }
    }
}

// ---------------- MFMA u/v via composite weights — single phase, no LDS ----------------
__global__ __launch_bounds__(128) void k_uv(
    const unsigned short* __restrict__ m2, const unsigned short* __restrict__ h16,
    const unsigned short* __restrict__ Wt, const float* __restrict__ buv,
    unsigned short* __restrict__ u16, unsigned short* __restrict__ v16) {
  const int l = threadIdx.x & 63;
  const int w = threadIdx.x >> 6;  // 0 -> u, 1 -> v
  const int cl = l & 15;
  const int kh = l >> 4;
  const int row0 = blockIdx.x * 32;  // grid 3125 exact
  const int ar0 = row0 + cl;
  const int ar1 = row0 + 16 + cl;
  const unsigned short* Wm = Wt + (long)(w ? 2 : 0) * 16384;
  const unsigned short* Wh = Wt + (long)(w ? 3 : 1) * 16384;

  f32x4 acc[2][8];
#pragma unroll
  for (int t = 0; t < 2; ++t)
#pragma unroll
    for (int nt = 0; nt < 8; ++nt) acc[t][nt] = (f32x4){0.f, 0.f, 0.f, 0.f};

#pragma unroll
  for (int s = 0; s < 4; ++s) {
    const int ko = s * 32 + kh * 8;
    bf16x8 am0 = *(const bf16x8*)(m2 + (long)ar0 * 128 + ko);
    bf16x8 ah0 = *(const bf16x8*)(h16 + (long)ar0 * 128 + ko);
    bf16x8 am1 = *(const bf16x8*)(m2 + (long)ar1 * 128 + ko);
    bf16x8 ah1 = *(const bf16x8*)(h16 + (long)ar1 * 128 + ko);
#pragma unroll
    for (int nt = 0; nt < 8; ++nt) {
      bf16x8 bm = *(const bf16x8*)(Wm + (long)(nt * 16 + cl) * 128 + ko);
      bf16x8 bh = *(const bf16x8*)(Wh + (long)(nt * 16 + cl) * 128 + ko);
      acc[0][nt] = __builtin_amdgcn_mfma_f32_16x16x32_bf16(am0, bm, acc[0][nt], 0, 0, 0);
      acc[0][nt] = __builtin_amdgcn_mfma_f32_16x16x32_bf16(ah0, bh, acc[0][nt], 0, 0, 0);
      acc[1][nt] = __builtin_amdgcn_mfma_f32_16x16x32_bf16(am1, bm, acc[1][nt], 0, 0, 0);
      acc[1][nt] = __builtin_amdgcn_mfma_f32_16x16x32_bf16(ah1, bh, acc[1][nt], 0, 0, 0);
    }
  }

  unsigned short* outp = w ? v16 : u16;
#pragma unroll
  for (int t = 0; t < 2; ++t)
#pragma unroll
    for (int nt = 0; nt < 8; ++nt) {
      float bb = buv[w * 128 + nt * 16 + cl];
#pragma unroll
      for (int i = 0; i < 4; ++i) {
        int r = row0 + t * 16 + kh * 4 + i;
        outp[(long)r * 128 + nt * 16 + cl] = f2bf(acc[t][nt][i] + bb);
      }
    }
}

// ---------------- per-label-edge decoder: bucketed, 16 lanes/edge ----------------
__global__ __launch_bounds__(256) void k_edge2(
    const int* __restrict__ lblcnt, const int2* __restrict__ lbin,
    const unsigned short* __restrict__ u16, const unsigned short* __restrict__ v16,
    const float* __restrict__ dw2, const float* __restrict__ db2,
    float* __restrict__ out) {
  const int lane = threadIdx.x & 63;
  const int wv = threadIdx.x >> 6;  // 0..3
  const int g = lane >> 4;          // edge slot within wave: 0..3
  const int q = lane & 15;
  const int b = blockIdx.x / (LCAP / 16);          // bucket
  const int chunk = blockIdx.x % (LCAP / 16);      // chunks of 16 slots
  const int idx = chunk * 16 + wv * 4 + g;
  if (idx >= lblcnt[b]) return;
  int2 rec = lbin[(long)b * LCAP + idx];
  int d = rec.x;
  int s = (b << 9) + (rec.y & 511);
  int e = rec.y >> 9;

  bf16x8 uu = *(const bf16x8*)(u16 + (long)s * 128 + q * 8);
  bf16x8 vv = *(const bf16x8*)(v16 + (long)d * 128 + q * 8);
  float4 w0 = *(const float4*)&dw2[q * 8];
  float4 w1 = *(const float4*)&dw2[q * 8 + 4];
  float w8[8] = {w0.x, w0.y, w0.z, w0.w, w1.x, w1.y, w1.z, w1.w};
  float sum = 0.0f;
#pragma unroll
  for (int i = 0; i < 8; ++i) {
    float h = fmaxf(bfs(uu[i]) + bfs(vv[i]), 0.0f);
    sum = fmaf(h, w8[i], sum);
  }
  sum += __shfl_xor(sum, 1);
  sum += __shfl_xor(sum, 2);
  sum += __shfl_xor(sum, 4);
  sum += __shfl_xor(sum, 8);
  if (q == 0) out[e] = sum + db2[0];
}

extern "C" void kernel_launch(void* const* d_in, const int* in_sizes, int n_in,
                              void* d_out, int out_size, void* d_ws, size_t ws_size,
                              hipStream_t stream) {
  const float* x   = (const float*)d_in[0];
  const int*   ei  = (const int*)d_in[1];
  const int*   eli = (const int*)d_in[2];
  const float* w1l = (const float*)d_in[3];
  const float* b1l = (const float*)d_in[4];
  const float* w1r = (const float*)d_in[5];
  const float* w2l = (const float*)d_in[6];
  const float* b2l = (const float*)d_in[7];
  const float* w2r = (const float*)d_in[8];
  const float* dw1 = (const float*)d_in[9];
  const float* db1 = (const float*)d_in[10];
  const float* dw2 = (const float*)d_in[11];
  const float* db2 = (const float*)d_in[12];
  float* out = (float*)d_out;

  // ---- workspace layout (byte offsets, 16B aligned) ----
  char* wsb = (char*)d_ws;
  float* inv     = (float*)(wsb + 0);              // 400000
  int*   deg_i   = (int*)(wsb + 400000);           // 400000
  int*   rowptr  = (int*)(wsb + 800000);           // 400032
  int*   gcursor = (int*)(wsb + 1200032);          // 1024
  int*   csr     = (int*)(wsb + 1201056);          // 6400000
  int*   binned  = (int*)(wsb + 7601056);          // 6400000
  unsigned short* x16  = (unsigned short*)(wsb + 14001056);   // 12.8 MB
  unsigned short* m1   = (unsigned short*)(wsb + 26801056);   // 12.8 MB
  unsigned short* u16  = (unsigned short*)(wsb + 14001056);   // 25.6 MB (aliases x16+m1)
  unsigned short* h16  = (unsigned short*)(wsb + 39601056);   // 25.6 MB
  unsigned short* m2   = (unsigned short*)(wsb + 65201056);   // 25.6 MB
  unsigned short* v16  = (unsigned short*)(wsb + 90801056);   // 25.6 MB
  unsigned short* w1lt = (unsigned short*)(wsb + 116401056);  // 16384
  unsigned short* w1rt = (unsigned short*)(wsb + 116417440);  // 16384
  unsigned short* Wt   = (unsigned short*)(wsb + 116433824);  // 131072 (4x 128x128 bf16)
  float* buv     = (float*)(wsb + 116564896);      // 1024
  int*   bsum    = (int*)(wsb + 116565920);        // 512
  int*   lblcnt  = (int*)(wsb + 116566432);        // 1024 (196 used)
  int2*  lbin    = (int2*)(wsb + 116567456);       // 4816896 -> ends ~121.4 MB

  const int* srcp = ei;
  const int* dstp = ei + N_EDGES;
  const int* lsp  = eli;
  const int* ldp  = eli + N_LBL;

  // ---- CSR build + label-edge binning + prep ----
  hipMemsetAsync(deg_i, 0, N_NODES * sizeof(int), stream);
  hipMemsetAsync(lblcnt, 0, NBUCK * sizeof(int), stream);
  k_deg<<<N_EDGES / 256, 256, 0, stream>>>(dstp, deg_i);
  k_scan_a<<<NSCANB, 1024, 0, stream>>>(deg_i, rowptr, inv, bsum);
  k_scan_b<<<1, 128, 0, stream>>>(bsum, rowptr);
  k_scan_c<<<NSCANB, 1024, 0, stream>>>(rowptr, bsum, gcursor);
  k_bin<<<(N_EDGES + 4095) / 4096, 256, 0, stream>>>(srcp, dstp, gcursor, binned);
  k_fill2<<<NBUCK, 256, 0, stream>>>(rowptr, binned, csr);
  k_lbl_bin<<<(N_LBL + 4095) / 4096, 256, 0, stream>>>(lsp, ldp, lblcnt, lbin);
  k_prep<<<(1616384 + 255) / 256, 256, 0, stream>>>(x, w1l, w1r, x16, w1lt, w1rt);
  k_prepw<<<257, 256, 0, stream>>>(w2l, w2r, dw1, b2l, db1, Wt, buv);

  // ---- layer 1 (MFMA) ----
  k_agg64<<<N_NODES / 4, 256, 0, stream>>>(rowptr, csr, x16, inv, m1);
  k_l1<<<(N_NODES + 127) / 128, 256, 0, stream>>>(m1, x16, w1lt, w1rt, b1l, h16);

  // ---- u/v via composite weights (single-phase MFMA) ----
  k_agg128<<<N_NODES / 4, 256, 0, stream>>>(rowptr, csr, h16, inv, m2);
  k_uv<<<N_NODES / 32, 128, 0, stream>>>(m2, h16, Wt, buv, u16, v16);

  // ---- decoder edge MLP (bucketed) ----
  k_edge2<<<NBUCK * (LCAP / 16), 256, 0, stream>>>(lblcnt, lbin, u16, v16, dw2, db2, out);
}